// Round 12
// baseline (281.560 us; speedup 1.0000x reference)
//
#include <hip/hip_runtime.h>

#define Bb 32
#define Nn 512
#define Dd 256
#define KC 1792   // 256 (self) + 6*256 (edge types)
#define NR (Bb * Nn)   // 16384 rows

typedef __bf16 bf16x8 __attribute__((ext_vector_type(8)));
typedef float  f32x4  __attribute__((ext_vector_type(4)));
typedef int    i32x4  __attribute__((ext_vector_type(4)));
typedef unsigned short u16;

__device__ __forceinline__ u16 f2bf(float x){
  union { float f; unsigned u; } c; c.f = x;
  unsigned u = c.u;
  u += 0x7FFFu + ((u >> 16) & 1u);   // RNE
  return (u16)(u >> 16);
}

// Ts swizzle: row-major [64][256] u16 with col8 ^= (row&7)  (T2)
#define TSW(row, col8) ((row) * 256 + (((col8) ^ ((row) & 7)) << 3))

// ---------------- K0: WcatT[e][c] = Wcat[c][e] in bf16, [256 x 1792] -------
__global__ __launch_bounds__(256) void k_prep(
    const float* __restrict__ wself,
    const float* __restrict__ w0, const float* __restrict__ w1,
    const float* __restrict__ w2, const float* __restrict__ w3,
    const float* __restrict__ w4, const float* __restrict__ w5,
    u16* __restrict__ wcatT){
  int e = blockIdx.x;
  const float* Ws[7] = {wself, w0, w1, w2, w3, w4, w5};
  for (int c = threadIdx.x; c < KC; c += 256){
    int g = c >> 8, j = c & 255;
    wcatT[(size_t)e*KC + c] = f2bf(Ws[g][j*Dd + e]);
  }
}

// ---------------- K1: bitpack graphs + nn (R10 version, accepted) ----------
#define GLD(d, p, o) asm volatile("global_load_dwordx4 %0, %1, off offset:" #o \
                                  : "=v"(d) : "v"(p))

__global__ __launch_bounds__(256) void k_pack(
    const int* __restrict__ g0, const int* __restrict__ g1,
    const int* __restrict__ g2, const int* __restrict__ g3,
    const int* __restrict__ g4, const int* __restrict__ g5,
    const int* __restrict__ mask,
    unsigned* __restrict__ Gp, float* __restrict__ rs){
  int t = threadIdx.x, l = t & 63, wv = t >> 6;
  int r = blockIdx.x * 4 + wv;          // r = b*512 + m
  int b = r >> 9, m = r & 511;
  size_t off = (size_t)r * Nn + l * 4;
  const int* pm = mask + (size_t)b * Nn + l * 4;
  const int* pa = g0 + off; const int* pb = g1 + off; const int* pcx = g2 + off;
  const int* pd = g3 + off; const int* pe = g4 + off; const int* pf = g5 + off;

  i32x4 A0,A1,B0,B1,C0,C1,D0,D1,E0,E1,F0,F1,M0,M1;
  GLD(M0,pm,0);  GLD(M1,pm,1024);
  GLD(A0,pa,0);  GLD(A1,pa,1024);
  GLD(B0,pb,0);  GLD(B1,pb,1024);
  GLD(C0,pcx,0); GLD(C1,pcx,1024);
  GLD(D0,pd,0);  GLD(D1,pd,1024);
  GLD(E0,pe,0);  GLD(E1,pe,1024);
  GLD(F0,pf,0);  GLD(F1,pf,1024);
  asm volatile("s_waitcnt vmcnt(0)" ::: "memory");
  __builtin_amdgcn_sched_barrier(0);

  int s1 = (l & 1) * 4, s2 = ((l >> 1) & 1) * 8, s3 = ((l >> 2) & 1) * 16;
  unsigned dm0 = ((m >> 2) == l)      ? (1u << (m & 3)) : 0u;
  unsigned dm1 = ((m >> 2) == 64 + l) ? (1u << (m & 3)) : 0u;
  int stot = 0;
#define PK(G, MM, DM, k, h) {                                              \
    unsigned nib = (unsigned)((G[0] & MM[0]) | ((G[1] & MM[1]) << 1) |     \
                              ((G[2] & MM[2]) << 2) | ((G[3] & MM[3]) << 3)) \
                   & ~(DM);                                                \
    stot += __popc(nib);                                                   \
    unsigned v = nib << s1; v |= (unsigned)__shfl_xor((int)v, 1);          \
    v <<= s2;               v |= (unsigned)__shfl_xor((int)v, 2);          \
    v <<= s3;               v |= (unsigned)__shfl_xor((int)v, 4);          \
    if ((l & 7) == 0)                                                      \
      Gp[((size_t)(k) * NR + r) * 16 + (h) * 8 + (l >> 3)] = v; }
  PK(A0,M0,dm0,0,0) PK(A1,M1,dm1,0,1)
  PK(B0,M0,dm0,1,0) PK(B1,M1,dm1,1,1)
  PK(C0,M0,dm0,2,0) PK(C1,M1,dm1,2,1)
  PK(D0,M0,dm0,3,0) PK(D1,M1,dm1,3,1)
  PK(E0,M0,dm0,4,0) PK(E1,M1,dm1,4,1)
  PK(F0,M0,dm0,5,0) PK(F1,M1,dm1,5,1)
#undef PK
  #pragma unroll
  for (int o = 1; o < 64; o <<= 1) stot += __shfl_xor(stot, o);
  if (l == 0)
    rs[r] = mask[r] ? 1.0f / (float)(stot < 1 ? 1 : stot) : 0.0f;
}
#undef GLD

// ---------------- K2: dw (sigmoid), Nbf bf16 node copy, X'^T build ---------
__global__ __launch_bounds__(256) void k_dw(
    const float* __restrict__ node, const int* __restrict__ mask,
    const float* __restrict__ wnw, const float* __restrict__ bnw,
    float* __restrict__ aw_out,    // already offset by t*N
    u16* __restrict__ Nbf, u16* __restrict__ XT){
  __shared__ float tile[32][268];
  __shared__ float dws[32];
  int b = blockIdx.x >> 4, n0 = (blockIdx.x & 15) << 5;
  int t = threadIdx.x;
  int row = t >> 3, seg = t & 7;
  const float* src = node + ((size_t)(b * Nn + n0 + row)) * Dd + seg * 32;
  u16* zn = Nbf + ((size_t)(b * Nn + n0 + row)) * Dd + seg * 32;
  #pragma unroll
  for (int c = 0; c < 8; ++c){
    float4 v = ((const float4*)src)[c];
    tile[row][seg * 32 + c * 4 + 0] = v.x;
    tile[row][seg * 32 + c * 4 + 1] = v.y;
    tile[row][seg * 32 + c * 4 + 2] = v.z;
    tile[row][seg * 32 + c * 4 + 3] = v.w;
    ushort4 h;
    h.x = f2bf(v.x); h.y = f2bf(v.y); h.z = f2bf(v.z); h.w = f2bf(v.w);
    ((ushort4*)zn)[c] = h;
  }
  __syncthreads();
  float s = 0.f;
  #pragma unroll
  for (int c = 0; c < 32; ++c) s += tile[row][seg * 32 + c] * wnw[seg * 32 + c];
  s += __shfl_xor(s, 1); s += __shfl_xor(s, 2); s += __shfl_xor(s, 4);
  if (seg == 0){
    float dw = 1.f / (1.f + expf(-(s + bnw[0])));
    aw_out[b * (2 * Nn) + n0 + row] = dw;
    dws[row] = mask[b * Nn + n0 + row] ? dw : 0.f;
  }
  __syncthreads();
  #pragma unroll
  for (int p = 0; p < 4; ++p){
    int d = p * 64 + (t >> 2);
    int j0 = (t & 3) * 8;
    union { u16 h[8]; uint4 v; } pk;
    #pragma unroll
    for (int jj = 0; jj < 8; ++jj)
      pk.h[jj] = f2bf(dws[j0 + jj] * tile[j0 + jj][d]);
    *(uint4*)(XT + ((size_t)(b * Dd + d)) * Nn + n0 + j0) = pk.v;
  }
}

// ---------------- K3: FUSED partials. grid (8, 32, 2): mtile, b, k-half ----
// z=0: k in {0,1,2,self}; z=1: k in {3,4,5}. Each writes f32 partial (no Z!).
// Per k: P1 = bitmask-GEMM T=G_k@X' -> Ts LDS (rs folded, XOR-swizzled);
// P2 = accO += Ts@W_k^T slices (wcatT from L2). 2 blocks/CU now co-resident.
__global__ __launch_bounds__(256) void k_fuse(
    const unsigned* __restrict__ Gp, const u16* __restrict__ XT,
    const u16* __restrict__ Nbf, const u16* __restrict__ wcatT,
    const float* __restrict__ rs, float* __restrict__ part){
  __shared__ u16 As[64 * 72];
  __shared__ u16 BW[256 * 72];        // X'^T slice (P1) / W^T slice (P2)
  __shared__ u16 Ts[64 * 256];        // XOR-swizzled
  int mt = blockIdx.x, b = blockIdx.y, z = blockIdx.z, m0 = mt * 64;
  int t = threadIdx.x, lane = t & 63, wn = t >> 6;
  int arow = t >> 2, aq = t & 3;
  const u16* Xb = XT + (size_t)b * Dd * Nn;
  float* myp = part + (size_t)z * ((size_t)NR * Dd);

  float rsv[16];
  #pragma unroll
  for (int i = 0; i < 4; ++i)
    #pragma unroll
    for (int r = 0; r < 4; ++r)
      rsv[i * 4 + r] = rs[b * Nn + m0 + i * 16 + (lane >> 4) * 4 + r];

  f32x4 accO[4][4];
  #pragma unroll
  for (int i = 0; i < 4; ++i)
    #pragma unroll
    for (int q = 0; q < 4; ++q) accO[i][q] = (f32x4){0.f, 0.f, 0.f, 0.f};

  int nk = (z == 0) ? 4 : 3;
  for (int ik = 0; ik < nk; ++ik){
    int k = (z == 0) ? ((ik == 3) ? 6 : ik) : (3 + ik);
    if (k < 6){
      // ---- P1: T = G_k @ X'  (64 x 256), rs folded on the way to LDS ----
      const unsigned* Gr = Gp + ((size_t)k * NR + b * Nn + m0) * 16;
      unsigned wpre[8];
      #pragma unroll
      for (int ks = 0; ks < 8; ++ks)
        wpre[ks] = Gr[arow * 16 + ks * 2 + (aq >> 1)];
      f32x4 Ta[4][4];
      #pragma unroll
      for (int i = 0; i < 4; ++i)
        #pragma unroll
        for (int q = 0; q < 4; ++q) Ta[i][q] = (f32x4){0.f, 0.f, 0.f, 0.f};

      for (int ks = 0; ks < 8; ++ks){
        int k0 = ks * 64;
        { // A stage: unpack 16 bits -> bf16 0/1
          unsigned bits = (wpre[ks] >> ((aq & 1) * 16)) & 0xFFFFu;
          union { u16 h[16]; uint4 v[2]; } pk;
          #pragma unroll
          for (int c = 0; c < 16; ++c)
            pk.h[c] = ((bits >> c) & 1u) ? 0x3F80 : 0;
          *(uint4*)&As[arow * 72 + aq * 16]     = pk.v[0];
          *(uint4*)&As[arow * 72 + aq * 16 + 8] = pk.v[1];
        }
        #pragma unroll
        for (int p = 0; p < 8; ++p){
          int rowb = p * 32 + (t >> 3);
          *(uint4*)&BW[rowb * 72 + (t & 7) * 8] =
              *(const uint4*)(Xb + (size_t)rowb * Nn + k0 + (t & 7) * 8);
        }
        __syncthreads();
        #pragma unroll
        for (int kk = 0; kk < 2; ++kk){
          bf16x8 av[4], bv[4];
          #pragma unroll
          for (int i = 0; i < 4; ++i)
            av[i] = *(const bf16x8*)&As[(i * 16 + (lane & 15)) * 72 + kk * 32 + (lane >> 4) * 8];
          #pragma unroll
          for (int q = 0; q < 4; ++q)
            bv[q] = *(const bf16x8*)&BW[(wn * 64 + q * 16 + (lane & 15)) * 72 + kk * 32 + (lane >> 4) * 8];
          #pragma unroll
          for (int i = 0; i < 4; ++i)
            #pragma unroll
            for (int q = 0; q < 4; ++q)
              Ta[i][q] = __builtin_amdgcn_mfma_f32_16x16x32_bf16(av[i], bv[q], Ta[i][q], 0, 0, 0);
        }
        __syncthreads();
      }
      // Ts[m][d] = bf16(Ta * rs[m]), swizzled
      #pragma unroll
      for (int i = 0; i < 4; ++i)
        #pragma unroll
        for (int r = 0; r < 4; ++r){
          int row = i * 16 + (lane >> 4) * 4 + r;
          #pragma unroll
          for (int q = 0; q < 4; ++q){
            int col = wn * 64 + q * 16 + (lane & 15);
            Ts[TSW(row, col >> 3) + (col & 7)] =
                f2bf(Ta[i][q][r] * rsv[i * 4 + r]);
          }
        }
      __syncthreads();
    } else {
      // ---- self term: Ts = bf16(node) tile from Nbf (swizzled) ----
      const u16* Nb = Nbf + ((size_t)(b * Nn + m0)) * Dd;
      #pragma unroll
      for (int p = 0; p < 8; ++p){
        int row = p * 8 + (t >> 5), col8 = t & 31;
        *(uint4*)&Ts[TSW(row, col8)] = *(const uint4*)(Nb + (size_t)row * Dd + col8 * 8);
      }
      __syncthreads();
    }
    // ---- P2: accO += Ts @ W^T slices ----
    int cb = (k < 6) ? (256 + k * 256) : 0;
    for (int cs = 0; cs < 4; ++cs){
      int c0 = cs * 64;
      #pragma unroll
      for (int p = 0; p < 8; ++p){
        int rowb = p * 32 + (t >> 3);
        *(uint4*)&BW[rowb * 72 + (t & 7) * 8] =
            *(const uint4*)(wcatT + (size_t)rowb * KC + cb + c0 + (t & 7) * 8);
      }
      __syncthreads();
      #pragma unroll
      for (int kk = 0; kk < 2; ++kk){
        bf16x8 av[4], bv[4];
        #pragma unroll
        for (int i = 0; i < 4; ++i){
          int row = i * 16 + (lane & 15);
          int col8 = ((c0 + kk * 32) >> 3) + (lane >> 4);
          av[i] = *(const bf16x8*)&Ts[TSW(row, col8)];
        }
        #pragma unroll
        for (int q = 0; q < 4; ++q)
          bv[q] = *(const bf16x8*)&BW[(wn * 64 + q * 16 + (lane & 15)) * 72 + kk * 32 + (lane >> 4) * 8];
        #pragma unroll
        for (int i = 0; i < 4; ++i)
          #pragma unroll
          for (int q = 0; q < 4; ++q)
            accO[i][q] = __builtin_amdgcn_mfma_f32_16x16x32_bf16(av[i], bv[q], accO[i][q], 0, 0, 0);
      }
      __syncthreads();
    }
  }
  // ---- epilogue: f32 partial -> part[z] ----
  #pragma unroll
  for (int i = 0; i < 4; ++i){
    #pragma unroll
    for (int r = 0; r < 4; ++r){
      size_t gr = (size_t)b * Nn + m0 + i * 16 + (lane >> 4) * 4 + r;
      #pragma unroll
      for (int q = 0; q < 4; ++q){
        int e = wn * 64 + q * 16 + (lane & 15);
        myp[gr * Dd + e] = accO[i][q][r];
      }
    }
  }
}

// ---------------- K4: combine  out = relu(p0 + p1 + bias) ------------------
__global__ __launch_bounds__(256) void k_comb(
    const float* __restrict__ part, const float* __restrict__ bself,
    float* __restrict__ outp){
  size_t i4 = (size_t)blockIdx.x * 256 + threadIdx.x;   // float4 index
  const float4* p0 = (const float4*)part;
  const float4* p1 = (const float4*)(part + (size_t)NR * Dd);
  float4 a = p0[i4], bq = p1[i4];
  float4 bias = *(const float4*)(bself + ((i4 * 4) & 255));
  float4 v;
  v.x = a.x + bq.x + bias.x; v.y = a.y + bq.y + bias.y;
  v.z = a.z + bq.z + bias.z; v.w = a.w + bq.w + bias.w;
  v.x = v.x > 0.f ? v.x : 0.f; v.y = v.y > 0.f ? v.y : 0.f;
  v.z = v.z > 0.f ? v.z : 0.f; v.w = v.w > 0.f ? v.w : 0.f;
  ((float4*)outp)[i4] = v;
}

extern "C" void kernel_launch(void* const* d_in, const int* in_sizes, int n_in,
                              void* d_out, int out_size, void* d_ws, size_t ws_size,
                              hipStream_t stream){
  (void)in_sizes; (void)n_in; (void)out_size; (void)ws_size;
  const float* node  = (const float*)d_in[0];
  const int*   mask  = (const int*)d_in[1];
  const int*   g[6];
  for (int i = 0; i < 6; ++i) g[i] = (const int*)d_in[2 + i];
  const float* wnw   = (const float*)d_in[8];
  const float* bnw   = (const float*)d_in[9];
  const float* wself = (const float*)d_in[10];
  const float* bself = (const float*)d_in[11];
  const float* W[6];
  for (int i = 0; i < 6; ++i) W[i] = (const float*)d_in[12 + i];

  float* out_node = (float*)d_out;
  float* out_aw   = out_node + (size_t)Bb * Nn * Dd;

  char* ws = (char*)d_ws;
  u16*      wcatT = (u16*)(ws);                    // 917,504 B
  float*    rs    = (float*)(ws + 917504);         // 65,536 B
  unsigned* Gp    = (unsigned*)(ws + 1048576);     // 6,291,456 B
  u16*      XT    = (u16*)(ws + 7340032);          // 8,388,608 B
  u16*      Nbf   = (u16*)(ws + 15728640);         // 8,388,608 B
  float*    part  = (float*)(ws + 24117248);       // 2 x 16,777,216 B -> ~55 MB

  k_prep<<<256, 256, 0, stream>>>(wself, W[0], W[1], W[2], W[3], W[4], W[5], wcatT);
  k_pack<<<4096, 256, 0, stream>>>(g[0], g[1], g[2], g[3], g[4], g[5], mask, Gp, rs);

  for (int t = 0; t < 2; ++t){
    const float* nsrc = (t == 0) ? node : out_node;   // iter-1 result lives in d_out
    k_dw<<<512, 256, 0, stream>>>(nsrc, mask, wnw, bnw, out_aw + t * Nn, Nbf, XT);
    k_fuse<<<dim3(8, 32, 2), 256, 0, stream>>>(Gp, XT, Nbf, wcatT, rs, part);
    k_comb<<<4096, 256, 0, stream>>>(part, bself, out_node);
  }
}

// Round 13
// 272.108 us; speedup vs baseline: 1.0347x; 1.0347x over previous
//
#include <hip/hip_runtime.h>

#define Bb 32
#define Nn 512
#define Dd 256
#define KC 1792   // 256 (self) + 6*256 (edge types)
#define NR (Bb * Nn)   // 16384 rows

typedef __bf16 bf16x8 __attribute__((ext_vector_type(8)));
typedef float  f32x4  __attribute__((ext_vector_type(4)));
typedef int    i32x4  __attribute__((ext_vector_type(4)));
typedef unsigned short u16;

__device__ __forceinline__ u16 f2bf(float x){
  union { float f; unsigned u; } c; c.f = x;
  unsigned u = c.u;
  u += 0x7FFFu + ((u >> 16) & 1u);   // RNE
  return (u16)(u >> 16);
}

// Ts swizzle: row-major [64][256] u16 with col8 ^= (row&7)  (T2)
#define TSW(row, col8) ((row) * 256 + (((col8) ^ ((row) & 7)) << 3))

// ---------------- K0: WcatT[e][c] = Wcat[c][e] in bf16, [256 x 1792] -------
__global__ __launch_bounds__(256) void k_prep(
    const float* __restrict__ wself,
    const float* __restrict__ w0, const float* __restrict__ w1,
    const float* __restrict__ w2, const float* __restrict__ w3,
    const float* __restrict__ w4, const float* __restrict__ w5,
    u16* __restrict__ wcatT){
  int e = blockIdx.x;
  const float* Ws[7] = {wself, w0, w1, w2, w3, w4, w5};
  for (int c = threadIdx.x; c < KC; c += 256){
    int g = c >> 8, j = c & 255;
    wcatT[(size_t)e*KC + c] = f2bf(Ws[g][j*Dd + e]);
  }
}

// ---------------- K1: bitpack graphs + nn (R10 version, accepted) ----------
#define GLD(d, p, o) asm volatile("global_load_dwordx4 %0, %1, off offset:" #o \
                                  : "=v"(d) : "v"(p))

__global__ __launch_bounds__(256) void k_pack(
    const int* __restrict__ g0, const int* __restrict__ g1,
    const int* __restrict__ g2, const int* __restrict__ g3,
    const int* __restrict__ g4, const int* __restrict__ g5,
    const int* __restrict__ mask,
    unsigned* __restrict__ Gp, float* __restrict__ rs){
  int t = threadIdx.x, l = t & 63, wv = t >> 6;
  int r = blockIdx.x * 4 + wv;          // r = b*512 + m
  int b = r >> 9, m = r & 511;
  size_t off = (size_t)r * Nn + l * 4;
  const int* pm = mask + (size_t)b * Nn + l * 4;
  const int* pa = g0 + off; const int* pb = g1 + off; const int* pcx = g2 + off;
  const int* pd = g3 + off; const int* pe = g4 + off; const int* pf = g5 + off;

  i32x4 A0,A1,B0,B1,C0,C1,D0,D1,E0,E1,F0,F1,M0,M1;
  GLD(M0,pm,0);  GLD(M1,pm,1024);
  GLD(A0,pa,0);  GLD(A1,pa,1024);
  GLD(B0,pb,0);  GLD(B1,pb,1024);
  GLD(C0,pcx,0); GLD(C1,pcx,1024);
  GLD(D0,pd,0);  GLD(D1,pd,1024);
  GLD(E0,pe,0);  GLD(E1,pe,1024);
  GLD(F0,pf,0);  GLD(F1,pf,1024);
  asm volatile("s_waitcnt vmcnt(0)" ::: "memory");
  __builtin_amdgcn_sched_barrier(0);

  int s1 = (l & 1) * 4, s2 = ((l >> 1) & 1) * 8, s3 = ((l >> 2) & 1) * 16;
  unsigned dm0 = ((m >> 2) == l)      ? (1u << (m & 3)) : 0u;
  unsigned dm1 = ((m >> 2) == 64 + l) ? (1u << (m & 3)) : 0u;
  int stot = 0;
#define PK(G, MM, DM, k, h) {                                              \
    unsigned nib = (unsigned)((G[0] & MM[0]) | ((G[1] & MM[1]) << 1) |     \
                              ((G[2] & MM[2]) << 2) | ((G[3] & MM[3]) << 3)) \
                   & ~(DM);                                                \
    stot += __popc(nib);                                                   \
    unsigned v = nib << s1; v |= (unsigned)__shfl_xor((int)v, 1);          \
    v <<= s2;               v |= (unsigned)__shfl_xor((int)v, 2);          \
    v <<= s3;               v |= (unsigned)__shfl_xor((int)v, 4);          \
    if ((l & 7) == 0)                                                      \
      Gp[((size_t)(k) * NR + r) * 16 + (h) * 8 + (l >> 3)] = v; }
  PK(A0,M0,dm0,0,0) PK(A1,M1,dm1,0,1)
  PK(B0,M0,dm0,1,0) PK(B1,M1,dm1,1,1)
  PK(C0,M0,dm0,2,0) PK(C1,M1,dm1,2,1)
  PK(D0,M0,dm0,3,0) PK(D1,M1,dm1,3,1)
  PK(E0,M0,dm0,4,0) PK(E1,M1,dm1,4,1)
  PK(F0,M0,dm0,5,0) PK(F1,M1,dm1,5,1)
#undef PK
  #pragma unroll
  for (int o = 1; o < 64; o <<= 1) stot += __shfl_xor(stot, o);
  if (l == 0)
    rs[r] = mask[r] ? 1.0f / (float)(stot < 1 ? 1 : stot) : 0.0f;
}
#undef GLD

// ---------------- K2: dw (sigmoid), Nbf bf16 node copy, X'^T build ---------
__global__ __launch_bounds__(256) void k_dw(
    const float* __restrict__ node, const int* __restrict__ mask,
    const float* __restrict__ wnw, const float* __restrict__ bnw,
    float* __restrict__ aw_out,    // already offset by t*N
    u16* __restrict__ Nbf, u16* __restrict__ XT){
  __shared__ float tile[32][268];
  __shared__ float dws[32];
  int b = blockIdx.x >> 4, n0 = (blockIdx.x & 15) << 5;
  int t = threadIdx.x;
  int row = t >> 3, seg = t & 7;
  const float* src = node + ((size_t)(b * Nn + n0 + row)) * Dd + seg * 32;
  u16* zn = Nbf + ((size_t)(b * Nn + n0 + row)) * Dd + seg * 32;
  #pragma unroll
  for (int c = 0; c < 8; ++c){
    float4 v = ((const float4*)src)[c];
    tile[row][seg * 32 + c * 4 + 0] = v.x;
    tile[row][seg * 32 + c * 4 + 1] = v.y;
    tile[row][seg * 32 + c * 4 + 2] = v.z;
    tile[row][seg * 32 + c * 4 + 3] = v.w;
    ushort4 h;
    h.x = f2bf(v.x); h.y = f2bf(v.y); h.z = f2bf(v.z); h.w = f2bf(v.w);
    ((ushort4*)zn)[c] = h;
  }
  __syncthreads();
  float s = 0.f;
  #pragma unroll
  for (int c = 0; c < 32; ++c) s += tile[row][seg * 32 + c] * wnw[seg * 32 + c];
  s += __shfl_xor(s, 1); s += __shfl_xor(s, 2); s += __shfl_xor(s, 4);
  if (seg == 0){
    float dw = 1.f / (1.f + expf(-(s + bnw[0])));
    aw_out[b * (2 * Nn) + n0 + row] = dw;
    dws[row] = mask[b * Nn + n0 + row] ? dw : 0.f;
  }
  __syncthreads();
  #pragma unroll
  for (int p = 0; p < 4; ++p){
    int d = p * 64 + (t >> 2);
    int j0 = (t & 3) * 8;
    union { u16 h[8]; uint4 v; } pk;
    #pragma unroll
    for (int jj = 0; jj < 8; ++jj)
      pk.h[jj] = f2bf(dws[j0 + jj] * tile[j0 + jj][d]);
    *(uint4*)(XT + ((size_t)(b * Dd + d)) * Nn + n0 + j0) = pk.v;
  }
}

// ---------------- K3: FUSED partials, XCD-locality swizzled ----------------
// 1-D grid 512. id -> xcd=id&7, q=id>>3: b = xcd*4+(q&3), mt=(q>>2)&7, z=q>>5.
// Each XCD's L2 then serves only 4 batches (4x262KB XT + wcatT ~ 2.1 MB).
// z=0: k in {0,1,2,self}; z=1: k in {3,4,5}; f32 partials, combined by k_comb.
__global__ __launch_bounds__(256) void k_fuse(
    const unsigned* __restrict__ Gp, const u16* __restrict__ XT,
    const u16* __restrict__ Nbf, const u16* __restrict__ wcatT,
    const float* __restrict__ rs, float* __restrict__ part){
  __shared__ u16 As[64 * 72];
  __shared__ u16 BW[256 * 72];        // X'^T slice (P1) / W^T slice (P2)
  __shared__ u16 Ts[64 * 256];        // XOR-swizzled
  int id = blockIdx.x;
  int xcd = id & 7, q = id >> 3;
  int b = xcd * 4 + (q & 3), mt = (q >> 2) & 7, z = q >> 5;
  int m0 = mt * 64;
  int t = threadIdx.x, lane = t & 63, wn = t >> 6;
  int arow = t >> 2, aq = t & 3;
  const u16* Xb = XT + (size_t)b * Dd * Nn;
  float* myp = part + (size_t)z * ((size_t)NR * Dd);

  float rsv[16];
  #pragma unroll
  for (int i = 0; i < 4; ++i)
    #pragma unroll
    for (int r = 0; r < 4; ++r)
      rsv[i * 4 + r] = rs[b * Nn + m0 + i * 16 + (lane >> 4) * 4 + r];

  f32x4 accO[4][4];
  #pragma unroll
  for (int i = 0; i < 4; ++i)
    #pragma unroll
    for (int q2 = 0; q2 < 4; ++q2) accO[i][q2] = (f32x4){0.f, 0.f, 0.f, 0.f};

  int nk = (z == 0) ? 4 : 3;
  for (int ik = 0; ik < nk; ++ik){
    int k = (z == 0) ? ((ik == 3) ? 6 : ik) : (3 + ik);
    if (k < 6){
      // ---- P1: T = G_k @ X'  (64 x 256), rs folded on the way to LDS ----
      const unsigned* Gr = Gp + ((size_t)k * NR + b * Nn + m0) * 16;
      unsigned wpre[8];
      #pragma unroll
      for (int ks = 0; ks < 8; ++ks)
        wpre[ks] = Gr[arow * 16 + ks * 2 + (aq >> 1)];
      f32x4 Ta[4][4];
      #pragma unroll
      for (int i = 0; i < 4; ++i)
        #pragma unroll
        for (int q2 = 0; q2 < 4; ++q2) Ta[i][q2] = (f32x4){0.f, 0.f, 0.f, 0.f};

      for (int ks = 0; ks < 8; ++ks){
        int k0 = ks * 64;
        { // A stage: unpack 16 bits -> bf16 0/1
          unsigned bits = (wpre[ks] >> ((aq & 1) * 16)) & 0xFFFFu;
          union { u16 h[16]; uint4 v[2]; } pk;
          #pragma unroll
          for (int c = 0; c < 16; ++c)
            pk.h[c] = ((bits >> c) & 1u) ? 0x3F80 : 0;
          *(uint4*)&As[arow * 72 + aq * 16]     = pk.v[0];
          *(uint4*)&As[arow * 72 + aq * 16 + 8] = pk.v[1];
        }
        #pragma unroll
        for (int p = 0; p < 8; ++p){
          int rowb = p * 32 + (t >> 3);
          *(uint4*)&BW[rowb * 72 + (t & 7) * 8] =
              *(const uint4*)(Xb + (size_t)rowb * Nn + k0 + (t & 7) * 8);
        }
        __syncthreads();
        #pragma unroll
        for (int kk = 0; kk < 2; ++kk){
          bf16x8 av[4], bv[4];
          #pragma unroll
          for (int i = 0; i < 4; ++i)
            av[i] = *(const bf16x8*)&As[(i * 16 + (lane & 15)) * 72 + kk * 32 + (lane >> 4) * 8];
          #pragma unroll
          for (int q2 = 0; q2 < 4; ++q2)
            bv[q2] = *(const bf16x8*)&BW[(wn * 64 + q2 * 16 + (lane & 15)) * 72 + kk * 32 + (lane >> 4) * 8];
          #pragma unroll
          for (int i = 0; i < 4; ++i)
            #pragma unroll
            for (int q2 = 0; q2 < 4; ++q2)
              Ta[i][q2] = __builtin_amdgcn_mfma_f32_16x16x32_bf16(av[i], bv[q2], Ta[i][q2], 0, 0, 0);
        }
        __syncthreads();
      }
      // Ts[m][d] = bf16(Ta * rs[m]), swizzled
      #pragma unroll
      for (int i = 0; i < 4; ++i)
        #pragma unroll
        for (int r = 0; r < 4; ++r){
          int row = i * 16 + (lane >> 4) * 4 + r;
          #pragma unroll
          for (int q2 = 0; q2 < 4; ++q2){
            int col = wn * 64 + q2 * 16 + (lane & 15);
            Ts[TSW(row, col >> 3) + (col & 7)] =
                f2bf(Ta[i][q2][r] * rsv[i * 4 + r]);
          }
        }
      __syncthreads();
    } else {
      // ---- self term: Ts = bf16(node) tile from Nbf (swizzled) ----
      const u16* Nb = Nbf + ((size_t)(b * Nn + m0)) * Dd;
      #pragma unroll
      for (int p = 0; p < 8; ++p){
        int row = p * 8 + (t >> 5), col8 = t & 31;
        *(uint4*)&Ts[TSW(row, col8)] = *(const uint4*)(Nb + (size_t)row * Dd + col8 * 8);
      }
      __syncthreads();
    }
    // ---- P2: accO += Ts @ W^T slices ----
    int cb = (k < 6) ? (256 + k * 256) : 0;
    for (int cs = 0; cs < 4; ++cs){
      int c0 = cs * 64;
      #pragma unroll
      for (int p = 0; p < 8; ++p){
        int rowb = p * 32 + (t >> 3);
        *(uint4*)&BW[rowb * 72 + (t & 7) * 8] =
            *(const uint4*)(wcatT + (size_t)rowb * KC + cb + c0 + (t & 7) * 8);
      }
      __syncthreads();
      #pragma unroll
      for (int kk = 0; kk < 2; ++kk){
        bf16x8 av[4], bv[4];
        #pragma unroll
        for (int i = 0; i < 4; ++i){
          int row = i * 16 + (lane & 15);
          int col8 = ((c0 + kk * 32) >> 3) + (lane >> 4);
          av[i] = *(const bf16x8*)&Ts[TSW(row, col8)];
        }
        #pragma unroll
        for (int q2 = 0; q2 < 4; ++q2)
          bv[q2] = *(const bf16x8*)&BW[(wn * 64 + q2 * 16 + (lane & 15)) * 72 + kk * 32 + (lane >> 4) * 8];
        #pragma unroll
        for (int i = 0; i < 4; ++i)
          #pragma unroll
          for (int q2 = 0; q2 < 4; ++q2)
            accO[i][q2] = __builtin_amdgcn_mfma_f32_16x16x32_bf16(av[i], bv[q2], accO[i][q2], 0, 0, 0);
      }
      __syncthreads();
    }
  }
  // ---- epilogue: f32 partial -> part[z] ----
  #pragma unroll
  for (int i = 0; i < 4; ++i){
    #pragma unroll
    for (int r = 0; r < 4; ++r){
      size_t gr = (size_t)b * Nn + m0 + i * 16 + (lane >> 4) * 4 + r;
      #pragma unroll
      for (int q2 = 0; q2 < 4; ++q2){
        int e = wn * 64 + q2 * 16 + (lane & 15);
        myp[gr * Dd + e] = accO[i][q2][r];
      }
    }
  }
}

// ---------------- K4: combine  out = relu(p0 + p1 + bias) ------------------
__global__ __launch_bounds__(256) void k_comb(
    const float* __restrict__ part, const float* __restrict__ bself,
    float* __restrict__ outp){
  size_t i4 = (size_t)blockIdx.x * 256 + threadIdx.x;   // float4 index
  const float4* p0 = (const float4*)part;
  const float4* p1 = (const float4*)(part + (size_t)NR * Dd);
  float4 a = p0[i4], bq = p1[i4];
  float4 bias = *(const float4*)(bself + ((i4 * 4) & 255));
  float4 v;
  v.x = a.x + bq.x + bias.x; v.y = a.y + bq.y + bias.y;
  v.z = a.z + bq.z + bias.z; v.w = a.w + bq.w + bias.w;
  v.x = v.x > 0.f ? v.x : 0.f; v.y = v.y > 0.f ? v.y : 0.f;
  v.z = v.z > 0.f ? v.z : 0.f; v.w = v.w > 0.f ? v.w : 0.f;
  ((float4*)outp)[i4] = v;
}

extern "C" void kernel_launch(void* const* d_in, const int* in_sizes, int n_in,
                              void* d_out, int out_size, void* d_ws, size_t ws_size,
                              hipStream_t stream){
  (void)in_sizes; (void)n_in; (void)out_size; (void)ws_size;
  const float* node  = (const float*)d_in[0];
  const int*   mask  = (const int*)d_in[1];
  const int*   g[6];
  for (int i = 0; i < 6; ++i) g[i] = (const int*)d_in[2 + i];
  const float* wnw   = (const float*)d_in[8];
  const float* bnw   = (const float*)d_in[9];
  const float* wself = (const float*)d_in[10];
  const float* bself = (const float*)d_in[11];
  const float* W[6];
  for (int i = 0; i < 6; ++i) W[i] = (const float*)d_in[12 + i];

  float* out_node = (float*)d_out;
  float* out_aw   = out_node + (size_t)Bb * Nn * Dd;

  char* ws = (char*)d_ws;
  u16*      wcatT = (u16*)(ws);                    // 917,504 B
  float*    rs    = (float*)(ws + 917504);         // 65,536 B
  unsigned* Gp    = (unsigned*)(ws + 1048576);     // 6,291,456 B
  u16*      XT    = (u16*)(ws + 7340032);          // 8,388,608 B
  u16*      Nbf   = (u16*)(ws + 15728640);         // 8,388,608 B
  float*    part  = (float*)(ws + 24117248);       // 2 x 16,777,216 B -> ~55 MB

  k_prep<<<256, 256, 0, stream>>>(wself, W[0], W[1], W[2], W[3], W[4], W[5], wcatT);
  k_pack<<<4096, 256, 0, stream>>>(g[0], g[1], g[2], g[3], g[4], g[5], mask, Gp, rs);

  for (int t = 0; t < 2; ++t){
    const float* nsrc = (t == 0) ? node : out_node;   // iter-1 result lives in d_out
    k_dw<<<512, 256, 0, stream>>>(nsrc, mask, wnw, bnw, out_aw + t * Nn, Nbf, XT);
    k_fuse<<<512, 256, 0, stream>>>(Gp, XT, Nbf, wcatT, rs, part);
    k_comb<<<4096, 256, 0, stream>>>(part, bself, out_node);
  }
}

// Round 14
// 243.421 us; speedup vs baseline: 1.1567x; 1.1178x over previous
//
#include <hip/hip_runtime.h>

#define Bb 32
#define Nn 512
#define Dd 256
#define KC 1792   // 256 (self) + 6*256 (edge types)
#define NR (Bb * Nn)   // 16384 rows

typedef __bf16 bf16x8 __attribute__((ext_vector_type(8)));
typedef float  f32x4  __attribute__((ext_vector_type(4)));
typedef int    i32x4  __attribute__((ext_vector_type(4)));
typedef unsigned short u16;

__device__ __forceinline__ u16 f2bf(float x){
  union { float f; unsigned u; } c; c.f = x;
  unsigned u = c.u;
  u += 0x7FFFu + ((u >> 16) & 1u);   // RNE
  return (u16)(u >> 16);
}

// ---------------- K0: WcatT[e][c] = Wcat[c][e] in bf16, [256 x 1792] -------
__global__ __launch_bounds__(256) void k_prep(
    const float* __restrict__ wself,
    const float* __restrict__ w0, const float* __restrict__ w1,
    const float* __restrict__ w2, const float* __restrict__ w3,
    const float* __restrict__ w4, const float* __restrict__ w5,
    u16* __restrict__ wcatT){
  int e = blockIdx.x;
  const float* Ws[7] = {wself, w0, w1, w2, w3, w4, w5};
  for (int c = threadIdx.x; c < KC; c += 256){
    int g = c >> 8, j = c & 255;
    wcatT[(size_t)e*KC + c] = f2bf(Ws[g][j*Dd + e]);
  }
}

// ---------------- K1: bitpack graphs + nn (R10 version, accepted) ----------
#define GLD(d, p, o) asm volatile("global_load_dwordx4 %0, %1, off offset:" #o \
                                  : "=v"(d) : "v"(p))

__global__ __launch_bounds__(256) void k_pack(
    const int* __restrict__ g0, const int* __restrict__ g1,
    const int* __restrict__ g2, const int* __restrict__ g3,
    const int* __restrict__ g4, const int* __restrict__ g5,
    const int* __restrict__ mask,
    unsigned* __restrict__ Gp, float* __restrict__ rs){
  int t = threadIdx.x, l = t & 63, wv = t >> 6;
  int r = blockIdx.x * 4 + wv;          // r = b*512 + m
  int b = r >> 9, m = r & 511;
  size_t off = (size_t)r * Nn + l * 4;
  const int* pm = mask + (size_t)b * Nn + l * 4;
  const int* pa = g0 + off; const int* pb = g1 + off; const int* pcx = g2 + off;
  const int* pd = g3 + off; const int* pe = g4 + off; const int* pf = g5 + off;

  i32x4 A0,A1,B0,B1,C0,C1,D0,D1,E0,E1,F0,F1,M0,M1;
  GLD(M0,pm,0);  GLD(M1,pm,1024);
  GLD(A0,pa,0);  GLD(A1,pa,1024);
  GLD(B0,pb,0);  GLD(B1,pb,1024);
  GLD(C0,pcx,0); GLD(C1,pcx,1024);
  GLD(D0,pd,0);  GLD(D1,pd,1024);
  GLD(E0,pe,0);  GLD(E1,pe,1024);
  GLD(F0,pf,0);  GLD(F1,pf,1024);
  asm volatile("s_waitcnt vmcnt(0)" ::: "memory");
  __builtin_amdgcn_sched_barrier(0);

  int s1 = (l & 1) * 4, s2 = ((l >> 1) & 1) * 8, s3 = ((l >> 2) & 1) * 16;
  unsigned dm0 = ((m >> 2) == l)      ? (1u << (m & 3)) : 0u;
  unsigned dm1 = ((m >> 2) == 64 + l) ? (1u << (m & 3)) : 0u;
  int stot = 0;
#define PK(G, MM, DM, k, h) {                                              \
    unsigned nib = (unsigned)((G[0] & MM[0]) | ((G[1] & MM[1]) << 1) |     \
                              ((G[2] & MM[2]) << 2) | ((G[3] & MM[3]) << 3)) \
                   & ~(DM);                                                \
    stot += __popc(nib);                                                   \
    unsigned v = nib << s1; v |= (unsigned)__shfl_xor((int)v, 1);          \
    v <<= s2;               v |= (unsigned)__shfl_xor((int)v, 2);          \
    v <<= s3;               v |= (unsigned)__shfl_xor((int)v, 4);          \
    if ((l & 7) == 0)                                                      \
      Gp[((size_t)(k) * NR + r) * 16 + (h) * 8 + (l >> 3)] = v; }
  PK(A0,M0,dm0,0,0) PK(A1,M1,dm1,0,1)
  PK(B0,M0,dm0,1,0) PK(B1,M1,dm1,1,1)
  PK(C0,M0,dm0,2,0) PK(C1,M1,dm1,2,1)
  PK(D0,M0,dm0,3,0) PK(D1,M1,dm1,3,1)
  PK(E0,M0,dm0,4,0) PK(E1,M1,dm1,4,1)
  PK(F0,M0,dm0,5,0) PK(F1,M1,dm1,5,1)
#undef PK
  #pragma unroll
  for (int o = 1; o < 64; o <<= 1) stot += __shfl_xor(stot, o);
  if (l == 0)
    rs[r] = mask[r] ? 1.0f / (float)(stot < 1 ? 1 : stot) : 0.0f;
}
#undef GLD

// ---------------- K2: dw (sigmoid), Nbf bf16 node copy, Xp = dw*node -------
__global__ __launch_bounds__(256) void k_dw(
    const float* __restrict__ node, const int* __restrict__ mask,
    const float* __restrict__ wnw, const float* __restrict__ bnw,
    float* __restrict__ aw_out,    // already offset by t*N
    u16* __restrict__ Nbf, u16* __restrict__ Xp){
  __shared__ float tile[32][268];
  __shared__ float dws[32];
  int b = blockIdx.x >> 4, n0 = (blockIdx.x & 15) << 5;
  int t = threadIdx.x;
  int row = t >> 3, seg = t & 7;
  const float* src = node + ((size_t)(b * Nn + n0 + row)) * Dd + seg * 32;
  u16* zn = Nbf + ((size_t)(b * Nn + n0 + row)) * Dd + seg * 32;
  #pragma unroll
  for (int c = 0; c < 8; ++c){
    float4 v = ((const float4*)src)[c];
    tile[row][seg * 32 + c * 4 + 0] = v.x;
    tile[row][seg * 32 + c * 4 + 1] = v.y;
    tile[row][seg * 32 + c * 4 + 2] = v.z;
    tile[row][seg * 32 + c * 4 + 3] = v.w;
    ushort4 h;
    h.x = f2bf(v.x); h.y = f2bf(v.y); h.z = f2bf(v.z); h.w = f2bf(v.w);
    ((ushort4*)zn)[c] = h;
  }
  __syncthreads();
  float s = 0.f;
  #pragma unroll
  for (int c = 0; c < 32; ++c) s += tile[row][seg * 32 + c] * wnw[seg * 32 + c];
  s += __shfl_xor(s, 1); s += __shfl_xor(s, 2); s += __shfl_xor(s, 4);
  if (seg == 0){
    float dw = 1.f / (1.f + expf(-(s + bnw[0])));
    aw_out[b * (2 * Nn) + n0 + row] = dw;
    dws[row] = mask[b * Nn + n0 + row] ? dw : 0.f;
  }
  __syncthreads();
  // Xp[n][d] = bf16(dw[n] * node[n][d])  (row-major, col-mask folded)
  {
    float dwr = dws[row];
    u16* xp = Xp + ((size_t)(b * Nn + n0 + row)) * Dd + seg * 32;
    #pragma unroll
    for (int c = 0; c < 8; ++c){
      ushort4 h;
      h.x = f2bf(dwr * tile[row][seg * 32 + c * 4 + 0]);
      h.y = f2bf(dwr * tile[row][seg * 32 + c * 4 + 1]);
      h.z = f2bf(dwr * tile[row][seg * 32 + c * 4 + 2]);
      h.w = f2bf(dwr * tile[row][seg * 32 + c * 4 + 3]);
      ((ushort4*)xp)[c] = h;
    }
  }
}

// ---------------- K3: Ycat GEMM  Yt[b][k][e][n] = (Xp[b] @ W_k)^T ----------
// grid (4, 12, 32): ntile, ctile(128 of 1536), b. 128x128 tile, K=256.
__global__ __launch_bounds__(256) void k_ycat(
    const u16* __restrict__ Xp, const u16* __restrict__ wcatT,
    u16* __restrict__ Yt){
  int n0 = blockIdx.x * 128, c0 = blockIdx.y * 128, b = blockIdx.z;
  int kg = c0 >> 8, eg0 = c0 & 255;
  __shared__ u16 As[128 * 72];
  __shared__ u16 Bs[128 * 72];
  int t = threadIdx.x, lane = t & 63, wid = t >> 6;
  int wm = wid >> 1, wn = wid & 1;
  f32x4 acc[4][4];
  #pragma unroll
  for (int i = 0; i < 4; ++i)
    #pragma unroll
    for (int q = 0; q < 4; ++q) acc[i][q] = (f32x4){0.f, 0.f, 0.f, 0.f};

  for (int ks = 0; ks < 4; ++ks){
    int k0 = ks * 64;
    #pragma unroll
    for (int p = 0; p < 4; ++p){
      int row = p * 32 + (t >> 3);
      *(uint4*)&As[row * 72 + (t & 7) * 8] =
          *(const uint4*)(Xp + ((size_t)(b * Nn + n0 + row)) * Dd + k0 + (t & 7) * 8);
      *(uint4*)&Bs[row * 72 + (t & 7) * 8] =
          *(const uint4*)(wcatT + (size_t)(eg0 + row) * KC + 256 + kg * 256 + k0 + (t & 7) * 8);
    }
    __syncthreads();
    #pragma unroll
    for (int kk = 0; kk < 2; ++kk){
      bf16x8 av[4], bv[4];
      #pragma unroll
      for (int i = 0; i < 4; ++i)
        av[i] = *(const bf16x8*)&As[(wm * 64 + i * 16 + (lane & 15)) * 72 + kk * 32 + (lane >> 4) * 8];
      #pragma unroll
      for (int q = 0; q < 4; ++q)
        bv[q] = *(const bf16x8*)&Bs[(wn * 64 + q * 16 + (lane & 15)) * 72 + kk * 32 + (lane >> 4) * 8];
      #pragma unroll
      for (int i = 0; i < 4; ++i)
        #pragma unroll
        for (int q = 0; q < 4; ++q)
          acc[i][q] = __builtin_amdgcn_mfma_f32_16x16x32_bf16(av[i], bv[q], acc[i][q], 0, 0, 0);
    }
    __syncthreads();
  }
  // epilogue: Yt[((b*6+kg)*256 + eg)][n], bf16, r-quad packed (n consecutive)
  #pragma unroll
  for (int i = 0; i < 4; ++i){
    int nbase = n0 + wm * 64 + i * 16 + (lane >> 4) * 4;
    #pragma unroll
    for (int q = 0; q < 4; ++q){
      int eg = eg0 + wn * 64 + q * 16 + (lane & 15);
      ushort4 h;
      h.x = f2bf(acc[i][q][0]); h.y = f2bf(acc[i][q][1]);
      h.z = f2bf(acc[i][q][2]); h.w = f2bf(acc[i][q][3]);
      *(ushort4*)(Yt + ((size_t)((b * 6 + kg) * 256 + eg)) * Nn + nbase) = h;
    }
  }
}

// ---------------- K4: aggregation  out = relu(rs*(Ĝ@Ŷ) + N@Wself + b) ------
// 1-D grid 512, XCD decode: b = (id&7)*4+(q&3), mt=(q>>2)&7, z=q>>5 (e-half).
// Tile 64m x 128e. 48 edge K-steps (bitmask A) + 4 self K-steps (Nbf A).
// LDS 27.6 KB -> multiple blocks/CU co-resident.
__global__ __launch_bounds__(256) void k_agg2(
    const unsigned* __restrict__ Gp, const u16* __restrict__ Yt,
    const u16* __restrict__ Nbf, const u16* __restrict__ wcatT,
    const float* __restrict__ rs, const float* __restrict__ bself,
    float* __restrict__ outp){
  __shared__ u16 As[64 * 72];
  __shared__ u16 BW[128 * 72];
  int id = blockIdx.x;
  int xcd = id & 7, q = id >> 3;
  int b = xcd * 4 + (q & 3), mt = (q >> 2) & 7, z = q >> 5;
  int m0 = mt * 64, e0 = z * 128;
  int t = threadIdx.x, lane = t & 63, wn = t >> 6;
  int arow = t >> 2, aq = t & 3;

  float rsv[16];
  #pragma unroll
  for (int i = 0; i < 4; ++i)
    #pragma unroll
    for (int r = 0; r < 4; ++r)
      rsv[i * 4 + r] = rs[b * Nn + m0 + i * 16 + (lane >> 4) * 4 + r];

  f32x4 accA[4][2], accS[4][2];
  #pragma unroll
  for (int i = 0; i < 4; ++i)
    #pragma unroll
    for (int q2 = 0; q2 < 2; ++q2){
      accA[i][q2] = (f32x4){0.f, 0.f, 0.f, 0.f};
      accS[i][q2] = (f32x4){0.f, 0.f, 0.f, 0.f};
    }

  for (int k = 0; k < 6; ++k){
    const unsigned* Gr = Gp + ((size_t)k * NR + b * Nn + m0) * 16;
    unsigned wpre[8];
    #pragma unroll
    for (int ks2 = 0; ks2 < 8; ++ks2)
      wpre[ks2] = Gr[arow * 16 + ks2 * 2 + (aq >> 1)];
    const u16* Yk = Yt + ((size_t)((b * 6 + k) * 256)) * Nn;

    for (int ks2 = 0; ks2 < 8; ++ks2){
      { // A stage: unpack 16 bits -> bf16 0/1
        unsigned bits = (wpre[ks2] >> ((aq & 1) * 16)) & 0xFFFFu;
        union { u16 h[16]; uint4 v[2]; } pk;
        #pragma unroll
        for (int c = 0; c < 16; ++c)
          pk.h[c] = ((bits >> c) & 1u) ? 0x3F80 : 0;
        *(uint4*)&As[arow * 72 + aq * 16]     = pk.v[0];
        *(uint4*)&As[arow * 72 + aq * 16 + 8] = pk.v[1];
      }
      #pragma unroll
      for (int p = 0; p < 4; ++p){
        int rowb = p * 32 + (t >> 3);
        *(uint4*)&BW[rowb * 72 + (t & 7) * 8] =
            *(const uint4*)(Yk + (size_t)(e0 + rowb) * Nn + ks2 * 64 + (t & 7) * 8);
      }
      __syncthreads();
      #pragma unroll
      for (int kk = 0; kk < 2; ++kk){
        bf16x8 av[4], bv[2];
        #pragma unroll
        for (int i = 0; i < 4; ++i)
          av[i] = *(const bf16x8*)&As[(i * 16 + (lane & 15)) * 72 + kk * 32 + (lane >> 4) * 8];
        #pragma unroll
        for (int q2 = 0; q2 < 2; ++q2)
          bv[q2] = *(const bf16x8*)&BW[(wn * 32 + q2 * 16 + (lane & 15)) * 72 + kk * 32 + (lane >> 4) * 8];
        #pragma unroll
        for (int i = 0; i < 4; ++i)
          #pragma unroll
          for (int q2 = 0; q2 < 2; ++q2)
            accA[i][q2] = __builtin_amdgcn_mfma_f32_16x16x32_bf16(av[i], bv[q2], accA[i][q2], 0, 0, 0);
      }
      __syncthreads();
    }
  }
  // ---- self term: 4 d-steps, A = Nbf tile, B = Wself^T ----
  for (int ds = 0; ds < 4; ++ds){
    #pragma unroll
    for (int p = 0; p < 2; ++p){
      int row = p * 32 + (t >> 3);
      *(uint4*)&As[row * 72 + (t & 7) * 8] =
          *(const uint4*)(Nbf + ((size_t)(b * Nn + m0 + row)) * Dd + ds * 64 + (t & 7) * 8);
    }
    #pragma unroll
    for (int p = 0; p < 4; ++p){
      int rowb = p * 32 + (t >> 3);
      *(uint4*)&BW[rowb * 72 + (t & 7) * 8] =
          *(const uint4*)(wcatT + (size_t)(e0 + rowb) * KC + ds * 64 + (t & 7) * 8);
    }
    __syncthreads();
    #pragma unroll
    for (int kk = 0; kk < 2; ++kk){
      bf16x8 av[4], bv[2];
      #pragma unroll
      for (int i = 0; i < 4; ++i)
        av[i] = *(const bf16x8*)&As[(i * 16 + (lane & 15)) * 72 + kk * 32 + (lane >> 4) * 8];
      #pragma unroll
      for (int q2 = 0; q2 < 2; ++q2)
        bv[q2] = *(const bf16x8*)&BW[(wn * 32 + q2 * 16 + (lane & 15)) * 72 + kk * 32 + (lane >> 4) * 8];
      #pragma unroll
      for (int i = 0; i < 4; ++i)
        #pragma unroll
        for (int q2 = 0; q2 < 2; ++q2)
          accS[i][q2] = __builtin_amdgcn_mfma_f32_16x16x32_bf16(av[i], bv[q2], accS[i][q2], 0, 0, 0);
    }
    __syncthreads();
  }
  // ---- epilogue: relu(rs*accA + accS + bias) -> out ----
  #pragma unroll
  for (int i = 0; i < 4; ++i){
    #pragma unroll
    for (int r = 0; r < 4; ++r){
      size_t gr = (size_t)b * Nn + m0 + i * 16 + (lane >> 4) * 4 + r;
      float rsm = rsv[i * 4 + r];
      #pragma unroll
      for (int q2 = 0; q2 < 2; ++q2){
        int col = e0 + wn * 32 + q2 * 16 + (lane & 15);
        float v = rsm * accA[i][q2][r] + accS[i][q2][r] + bself[col];
        outp[gr * Dd + col] = v > 0.f ? v : 0.f;
      }
    }
  }
}

extern "C" void kernel_launch(void* const* d_in, const int* in_sizes, int n_in,
                              void* d_out, int out_size, void* d_ws, size_t ws_size,
                              hipStream_t stream){
  (void)in_sizes; (void)n_in; (void)out_size; (void)ws_size;
  const float* node  = (const float*)d_in[0];
  const int*   mask  = (const int*)d_in[1];
  const int*   g[6];
  for (int i = 0; i < 6; ++i) g[i] = (const int*)d_in[2 + i];
  const float* wnw   = (const float*)d_in[8];
  const float* bnw   = (const float*)d_in[9];
  const float* wself = (const float*)d_in[10];
  const float* bself = (const float*)d_in[11];
  const float* W[6];
  for (int i = 0; i < 6; ++i) W[i] = (const float*)d_in[12 + i];

  float* out_node = (float*)d_out;
  float* out_aw   = out_node + (size_t)Bb * Nn * Dd;

  char* ws = (char*)d_ws;
  u16*      wcatT = (u16*)(ws);                    // 917,504 B
  float*    rs    = (float*)(ws + 917504);         // 65,536 B
  unsigned* Gp    = (unsigned*)(ws + 1048576);     // 6,291,456 B
  u16*      Xp    = (u16*)(ws + 7340032);          // 8,388,608 B
  u16*      Nbf   = (u16*)(ws + 15728640);         // 8,388,608 B
  u16*      Yt    = (u16*)(ws + 24117248);         // 50,331,648 B -> ends ~74.4 MB

  k_prep<<<256, 256, 0, stream>>>(wself, W[0], W[1], W[2], W[3], W[4], W[5], wcatT);
  k_pack<<<4096, 256, 0, stream>>>(g[0], g[1], g[2], g[3], g[4], g[5], mask, Gp, rs);

  for (int t = 0; t < 2; ++t){
    const float* nsrc = (t == 0) ? node : out_node;   // iter-1 result lives in d_out
    k_dw<<<512, 256, 0, stream>>>(nsrc, mask, wnw, bnw, out_aw + t * Nn, Nbf, Xp);
    k_ycat<<<dim3(4, 12, 32), 256, 0, stream>>>(Xp, wcatT, Yt);
    k_agg2<<<512, 256, 0, stream>>>(Gp, Yt, Nbf, wcatT, rs, bself, out_node);
  }
}

// Round 15
// 242.395 us; speedup vs baseline: 1.1616x; 1.0042x over previous
//
#include <hip/hip_runtime.h>

#define Bb 32
#define Nn 512
#define Dd 256
#define KC 1792   // 256 (self) + 6*256 (edge types)
#define NR (Bb * Nn)   // 16384 rows

typedef __bf16 bf16x8 __attribute__((ext_vector_type(8)));
typedef float  f32x4  __attribute__((ext_vector_type(4)));
typedef int    i32x4  __attribute__((ext_vector_type(4)));
typedef unsigned short u16;

__device__ __forceinline__ u16 f2bf(float x){
  union { float f; unsigned u; } c; c.f = x;
  unsigned u = c.u;
  u += 0x7FFFu + ((u >> 16) & 1u);   // RNE
  return (u16)(u >> 16);
}

// ---------------- K0: WcatT[e][c] = Wcat[c][e] in bf16, [256 x 1792] -------
__global__ __launch_bounds__(256) void k_prep(
    const float* __restrict__ wself,
    const float* __restrict__ w0, const float* __restrict__ w1,
    const float* __restrict__ w2, const float* __restrict__ w3,
    const float* __restrict__ w4, const float* __restrict__ w5,
    u16* __restrict__ wcatT){
  int e = blockIdx.x;
  const float* Ws[7] = {wself, w0, w1, w2, w3, w4, w5};
  for (int c = threadIdx.x; c < KC; c += 256){
    int g = c >> 8, j = c & 255;
    wcatT[(size_t)e*KC + c] = f2bf(Ws[g][j*Dd + e]);
  }
}

// ---------------- K2: dw (sigmoid), Nbf bf16 node copy, Xp = dw*node -------
__global__ __launch_bounds__(256) void k_dw(
    const float* __restrict__ node, const int* __restrict__ mask,
    const float* __restrict__ wnw, const float* __restrict__ bnw,
    float* __restrict__ aw_out,    // already offset by t*N
    u16* __restrict__ Nbf, u16* __restrict__ Xp){
  __shared__ float tile[32][268];
  __shared__ float dws[32];
  int b = blockIdx.x >> 4, n0 = (blockIdx.x & 15) << 5;
  int t = threadIdx.x;
  int row = t >> 3, seg = t & 7;
  const float* src = node + ((size_t)(b * Nn + n0 + row)) * Dd + seg * 32;
  u16* zn = Nbf + ((size_t)(b * Nn + n0 + row)) * Dd + seg * 32;
  #pragma unroll
  for (int c = 0; c < 8; ++c){
    float4 v = ((const float4*)src)[c];
    tile[row][seg * 32 + c * 4 + 0] = v.x;
    tile[row][seg * 32 + c * 4 + 1] = v.y;
    tile[row][seg * 32 + c * 4 + 2] = v.z;
    tile[row][seg * 32 + c * 4 + 3] = v.w;
    ushort4 h;
    h.x = f2bf(v.x); h.y = f2bf(v.y); h.z = f2bf(v.z); h.w = f2bf(v.w);
    ((ushort4*)zn)[c] = h;
  }
  __syncthreads();
  float s = 0.f;
  #pragma unroll
  for (int c = 0; c < 32; ++c) s += tile[row][seg * 32 + c] * wnw[seg * 32 + c];
  s += __shfl_xor(s, 1); s += __shfl_xor(s, 2); s += __shfl_xor(s, 4);
  if (seg == 0){
    float dw = 1.f / (1.f + expf(-(s + bnw[0])));
    aw_out[b * (2 * Nn) + n0 + row] = dw;
    dws[row] = mask[b * Nn + n0 + row] ? dw : 0.f;
  }
  __syncthreads();
  // Xp[n][d] = bf16(dw[n] * node[n][d])  (row-major, col-mask folded)
  {
    float dwr = dws[row];
    u16* xp = Xp + ((size_t)(b * Nn + n0 + row)) * Dd + seg * 32;
    #pragma unroll
    for (int c = 0; c < 8; ++c){
      ushort4 h;
      h.x = f2bf(dwr * tile[row][seg * 32 + c * 4 + 0]);
      h.y = f2bf(dwr * tile[row][seg * 32 + c * 4 + 1]);
      h.z = f2bf(dwr * tile[row][seg * 32 + c * 4 + 2]);
      h.w = f2bf(dwr * tile[row][seg * 32 + c * 4 + 3]);
      ((ushort4*)xp)[c] = h;
    }
  }
}

// ---------------- K3: Ycat GEMM  Yt[b][k][e][n] = (Xp[b] @ W_k)^T ----------
// grid (4, 12, 32): ntile, ctile(128 of 1536), b. 128x128 tile, K=256.
__global__ __launch_bounds__(256) void k_ycat(
    const u16* __restrict__ Xp, const u16* __restrict__ wcatT,
    u16* __restrict__ Yt){
  int n0 = blockIdx.x * 128, c0 = blockIdx.y * 128, b = blockIdx.z;
  int kg = c0 >> 8, eg0 = c0 & 255;
  __shared__ u16 As[128 * 72];
  __shared__ u16 Bs[128 * 72];
  int t = threadIdx.x, lane = t & 63, wid = t >> 6;
  int wm = wid >> 1, wn = wid & 1;
  f32x4 acc[4][4];
  #pragma unroll
  for (int i = 0; i < 4; ++i)
    #pragma unroll
    for (int q = 0; q < 4; ++q) acc[i][q] = (f32x4){0.f, 0.f, 0.f, 0.f};

  for (int ks = 0; ks < 4; ++ks){
    int k0 = ks * 64;
    #pragma unroll
    for (int p = 0; p < 4; ++p){
      int row = p * 32 + (t >> 3);
      *(uint4*)&As[row * 72 + (t & 7) * 8] =
          *(const uint4*)(Xp + ((size_t)(b * Nn + n0 + row)) * Dd + k0 + (t & 7) * 8);
      *(uint4*)&Bs[row * 72 + (t & 7) * 8] =
          *(const uint4*)(wcatT + (size_t)(eg0 + row) * KC + 256 + kg * 256 + k0 + (t & 7) * 8);
    }
    __syncthreads();
    #pragma unroll
    for (int kk = 0; kk < 2; ++kk){
      bf16x8 av[4], bv[4];
      #pragma unroll
      for (int i = 0; i < 4; ++i)
        av[i] = *(const bf16x8*)&As[(wm * 64 + i * 16 + (lane & 15)) * 72 + kk * 32 + (lane >> 4) * 8];
      #pragma unroll
      for (int q = 0; q < 4; ++q)
        bv[q] = *(const bf16x8*)&Bs[(wn * 64 + q * 16 + (lane & 15)) * 72 + kk * 32 + (lane >> 4) * 8];
      #pragma unroll
      for (int i = 0; i < 4; ++i)
        #pragma unroll
        for (int q = 0; q < 4; ++q)
          acc[i][q] = __builtin_amdgcn_mfma_f32_16x16x32_bf16(av[i], bv[q], acc[i][q], 0, 0, 0);
    }
    __syncthreads();
  }
  #pragma unroll
  for (int i = 0; i < 4; ++i){
    int nbase = n0 + wm * 64 + i * 16 + (lane >> 4) * 4;
    #pragma unroll
    for (int q = 0; q < 4; ++q){
      int eg = eg0 + wn * 64 + q * 16 + (lane & 15);
      ushort4 h;
      h.x = f2bf(acc[i][q][0]); h.y = f2bf(acc[i][q][1]);
      h.z = f2bf(acc[i][q][2]); h.w = f2bf(acc[i][q][3]);
      *(ushort4*)(Yt + ((size_t)((b * 6 + kg) * 256 + eg)) * Nn + nbase) = h;
    }
  }
}

// ---------------- K4a: ITER-1 aggregation from RAW graphs ------------------
// out = relu(rs*(G@Y) + N@Wself + b); side effects: Gp bits, rs (for iter 2).
// 1-D grid 512, XCD decode: b=(id&7)*4+(q&3), mt=q>>2 (BM=32), full e=256.
// A-stage: raw int32 G -> bf16 0/1 (diag folded); nn popcount in-flight.
__global__ __launch_bounds__(256) void k_agg1(
    const int* __restrict__ g0, const int* __restrict__ g1,
    const int* __restrict__ g2, const int* __restrict__ g3,
    const int* __restrict__ g4, const int* __restrict__ g5,
    const int* __restrict__ mask, const u16* __restrict__ Yt,
    const u16* __restrict__ Nbf, const u16* __restrict__ wcatT,
    const float* __restrict__ bself,
    unsigned char* __restrict__ Gp8, float* __restrict__ rs,
    float* __restrict__ outp){
  __shared__ u16 As[32 * 72];
  __shared__ u16 BW[256 * 72];
  __shared__ int nns[32][9];
  __shared__ float rsl[32];
  __shared__ unsigned char lmask8[64];
  const int* gs[6] = {g0, g1, g2, g3, g4, g5};
  int id = blockIdx.x;
  int xcd = id & 7, q = id >> 3;
  int b = xcd * 4 + (q & 3), mt = q >> 2;
  int m0 = mt * 32;
  int t = threadIdx.x, lane = t & 63, wn = t >> 6;
  int arow = t >> 3, q8 = t & 7;          // A-stage role: row 0..31, 8 cols
  int mloc = m0 + arow;                   // diag col for this row

  // pack column-mask bits once (64 bytes)
  if (t < 64){
    const int* mp = mask + (size_t)b * Nn + t * 8;
    unsigned mb = 0;
    #pragma unroll
    for (int j = 0; j < 8; ++j) mb |= (unsigned)(mp[j] & 1) << j;
    lmask8[t] = (unsigned char)mb;
  }
  __syncthreads();

  f32x4 acc[2][4];
  #pragma unroll
  for (int i = 0; i < 2; ++i)
    #pragma unroll
    for (int q2 = 0; q2 < 4; ++q2) acc[i][q2] = (f32x4){0.f, 0.f, 0.f, 0.f};

  int nnp = 0;
  for (int k = 0; k < 6; ++k){
    const int* Gk = gs[k] + ((size_t)(b * Nn + m0)) * Nn;
    const u16* Yk = Yt + ((size_t)((b * 6 + k) * 256)) * Nn;
    for (int ks = 0; ks < 8; ++ks){
      { // A stage: 8 raw ints -> 8-bit mask -> bf16 + popcount + Gp byte
        const i32x4* gp = (const i32x4*)(Gk + (size_t)arow * Nn + ks * 64 + q8 * 8);
        i32x4 x0 = gp[0], x1 = gp[1];
        unsigned bits = (unsigned)((x0[0] & 1) | ((x0[1] & 1) << 1) |
                                   ((x0[2] & 1) << 2) | ((x0[3] & 1) << 3) |
                                   ((x1[0] & 1) << 4) | ((x1[1] & 1) << 5) |
                                   ((x1[2] & 1) << 6) | ((x1[3] & 1) << 7));
        unsigned dm = ((mloc >> 3) == (ks * 8 + q8)) ? (1u << (mloc & 7)) : 0u;
        bits &= ~dm;                      // diag excluded (GEMM + count)
        unsigned mb = lmask8[ks * 8 + q8];
        unsigned bm = bits & mb;          // col-mask for count + Gp
        nnp += __popc(bm);
        Gp8[(((size_t)k * NR + b * Nn + m0 + arow) * 16 + ks * 2 + (q8 >> 2)) * 4 + (q8 & 3)] =
            (unsigned char)bm;
        union { u16 h[8]; uint4 v; } pk;
        #pragma unroll
        for (int c = 0; c < 8; ++c)
          pk.h[c] = ((bits >> c) & 1u) ? 0x3F80 : 0;
        *(uint4*)&As[arow * 72 + q8 * 8] = pk.v;
      }
      #pragma unroll
      for (int p = 0; p < 8; ++p){
        int rowb = p * 32 + (t >> 3);
        *(uint4*)&BW[rowb * 72 + (t & 7) * 8] =
            *(const uint4*)(Yk + (size_t)rowb * Nn + ks * 64 + (t & 7) * 8);
      }
      __syncthreads();
      #pragma unroll
      for (int kk = 0; kk < 2; ++kk){
        bf16x8 av[2], bv[4];
        #pragma unroll
        for (int i = 0; i < 2; ++i)
          av[i] = *(const bf16x8*)&As[(i * 16 + (lane & 15)) * 72 + kk * 32 + (lane >> 4) * 8];
        #pragma unroll
        for (int q2 = 0; q2 < 4; ++q2)
          bv[q2] = *(const bf16x8*)&BW[(wn * 64 + q2 * 16 + (lane & 15)) * 72 + kk * 32 + (lane >> 4) * 8];
        #pragma unroll
        for (int i = 0; i < 2; ++i)
          #pragma unroll
          for (int q2 = 0; q2 < 4; ++q2)
            acc[i][q2] = __builtin_amdgcn_mfma_f32_16x16x32_bf16(av[i], bv[q2], acc[i][q2], 0, 0, 0);
      }
      __syncthreads();
    }
  }
  // ---- nn reduce -> rs (LDS + global) ----
  nns[arow][q8] = nnp;
  __syncthreads();
  if (t < 32){
    int s = 0;
    #pragma unroll
    for (int j = 0; j < 8; ++j) s += nns[t][j];
    int r = b * Nn + m0 + t;
    float v = mask[r] ? 1.0f / (float)(s < 1 ? 1 : s) : 0.0f;
    rsl[t] = v;
    rs[r] = v;
  }
  __syncthreads();
  // ---- scale edge acc by rs, then accumulate self term on top ----
  #pragma unroll
  for (int i = 0; i < 2; ++i)
    #pragma unroll
    for (int rr = 0; rr < 4; ++rr){
      float s = rsl[i * 16 + (lane >> 4) * 4 + rr];
      #pragma unroll
      for (int q2 = 0; q2 < 4; ++q2) acc[i][q2][rr] *= s;
    }
  for (int ds = 0; ds < 4; ++ds){
    if (t < 256){ // A: Nbf tile 32x64
      *(uint4*)&As[(t >> 3) * 72 + (t & 7) * 8] =
          *(const uint4*)(Nbf + ((size_t)(b * Nn + m0 + (t >> 3))) * Dd + ds * 64 + (t & 7) * 8);
    }
    #pragma unroll
    for (int p = 0; p < 8; ++p){
      int rowb = p * 32 + (t >> 3);
      *(uint4*)&BW[rowb * 72 + (t & 7) * 8] =
          *(const uint4*)(wcatT + (size_t)rowb * KC + ds * 64 + (t & 7) * 8);
    }
    __syncthreads();
    #pragma unroll
    for (int kk = 0; kk < 2; ++kk){
      bf16x8 av[2], bv[4];
      #pragma unroll
      for (int i = 0; i < 2; ++i)
        av[i] = *(const bf16x8*)&As[(i * 16 + (lane & 15)) * 72 + kk * 32 + (lane >> 4) * 8];
      #pragma unroll
      for (int q2 = 0; q2 < 4; ++q2)
        bv[q2] = *(const bf16x8*)&BW[(wn * 64 + q2 * 16 + (lane & 15)) * 72 + kk * 32 + (lane >> 4) * 8];
      #pragma unroll
      for (int i = 0; i < 2; ++i)
        #pragma unroll
        for (int q2 = 0; q2 < 4; ++q2)
          acc[i][q2] = __builtin_amdgcn_mfma_f32_16x16x32_bf16(av[i], bv[q2], acc[i][q2], 0, 0, 0);
    }
    __syncthreads();
  }
  // ---- epilogue ----
  #pragma unroll
  for (int i = 0; i < 2; ++i){
    #pragma unroll
    for (int rr = 0; rr < 4; ++rr){
      size_t gr = (size_t)b * Nn + m0 + i * 16 + (lane >> 4) * 4 + rr;
      #pragma unroll
      for (int q2 = 0; q2 < 4; ++q2){
        int col = wn * 64 + q2 * 16 + (lane & 15);
        float v = acc[i][q2][rr] + bself[col];
        outp[gr * Dd + col] = v > 0.f ? v : 0.f;
      }
    }
  }
}

// ---------------- K4b: ITER-2 aggregation from PACKED graphs ---------------
// 1-D grid 512, XCD decode: b=(id&7)*4+(q&3), mt=(q>>2)&7, z=q>>5 (e-half).
// Tile 64m x 128e. 48 edge K-steps (bitmask A) + rs-scale + 4 self K-steps.
__global__ __launch_bounds__(256) void k_agg2(
    const unsigned* __restrict__ Gp, const u16* __restrict__ Yt,
    const u16* __restrict__ Nbf, const u16* __restrict__ wcatT,
    const float* __restrict__ rs, const float* __restrict__ bself,
    float* __restrict__ outp){
  __shared__ u16 As[64 * 72];
  __shared__ u16 BW[128 * 72];
  int id = blockIdx.x;
  int xcd = id & 7, q = id >> 3;
  int b = xcd * 4 + (q & 3), mt = (q >> 2) & 7, z = q >> 5;
  int m0 = mt * 64, e0 = z * 128;
  int t = threadIdx.x, lane = t & 63, wn = t >> 6;
  int arow = t >> 2, aq = t & 3;

  float rsv[16];
  #pragma unroll
  for (int i = 0; i < 4; ++i)
    #pragma unroll
    for (int r = 0; r < 4; ++r)
      rsv[i * 4 + r] = rs[b * Nn + m0 + i * 16 + (lane >> 4) * 4 + r];

  f32x4 accA[4][2];
  #pragma unroll
  for (int i = 0; i < 4; ++i)
    #pragma unroll
    for (int q2 = 0; q2 < 2; ++q2)
      accA[i][q2] = (f32x4){0.f, 0.f, 0.f, 0.f};

  for (int k = 0; k < 6; ++k){
    const unsigned* Gr = Gp + ((size_t)k * NR + b * Nn + m0) * 16;
    unsigned wpre[8];
    #pragma unroll
    for (int ks2 = 0; ks2 < 8; ++ks2)
      wpre[ks2] = Gr[arow * 16 + ks2 * 2 + (aq >> 1)];
    const u16* Yk = Yt + ((size_t)((b * 6 + k) * 256)) * Nn;

    for (int ks2 = 0; ks2 < 8; ++ks2){
      { // A stage: unpack 16 bits -> bf16 0/1
        unsigned bits = (wpre[ks2] >> ((aq & 1) * 16)) & 0xFFFFu;
        union { u16 h[16]; uint4 v[2]; } pk;
        #pragma unroll
        for (int c = 0; c < 16; ++c)
          pk.h[c] = ((bits >> c) & 1u) ? 0x3F80 : 0;
        *(uint4*)&As[arow * 72 + aq * 16]     = pk.v[0];
        *(uint4*)&As[arow * 72 + aq * 16 + 8] = pk.v[1];
      }
      #pragma unroll
      for (int p = 0; p < 4; ++p){
        int rowb = p * 32 + (t >> 3);
        *(uint4*)&BW[rowb * 72 + (t & 7) * 8] =
            *(const uint4*)(Yk + (size_t)(e0 + rowb) * Nn + ks2 * 64 + (t & 7) * 8);
      }
      __syncthreads();
      #pragma unroll
      for (int kk = 0; kk < 2; ++kk){
        bf16x8 av[4], bv[2];
        #pragma unroll
        for (int i = 0; i < 4; ++i)
          av[i] = *(const bf16x8*)&As[(i * 16 + (lane & 15)) * 72 + kk * 32 + (lane >> 4) * 8];
        #pragma unroll
        for (int q2 = 0; q2 < 2; ++q2)
          bv[q2] = *(const bf16x8*)&BW[(wn * 32 + q2 * 16 + (lane & 15)) * 72 + kk * 32 + (lane >> 4) * 8];
        #pragma unroll
        for (int i = 0; i < 4; ++i)
          #pragma unroll
          for (int q2 = 0; q2 < 2; ++q2)
            accA[i][q2] = __builtin_amdgcn_mfma_f32_16x16x32_bf16(av[i], bv[q2], accA[i][q2], 0, 0, 0);
      }
      __syncthreads();
    }
  }
  // ---- scale by rs, then accumulate self term on top ----
  #pragma unroll
  for (int i = 0; i < 4; ++i)
    #pragma unroll
    for (int rr = 0; rr < 4; ++rr){
      float s = rsv[i * 4 + rr];
      #pragma unroll
      for (int q2 = 0; q2 < 2; ++q2) accA[i][q2][rr] *= s;
    }
  for (int ds = 0; ds < 4; ++ds){
    #pragma unroll
    for (int p = 0; p < 2; ++p){
      int row = p * 32 + (t >> 3);
      *(uint4*)&As[row * 72 + (t & 7) * 8] =
          *(const uint4*)(Nbf + ((size_t)(b * Nn + m0 + row)) * Dd + ds * 64 + (t & 7) * 8);
    }
    #pragma unroll
    for (int p = 0; p < 4; ++p){
      int rowb = p * 32 + (t >> 3);
      *(uint4*)&BW[rowb * 72 + (t & 7) * 8] =
          *(const uint4*)(wcatT + (size_t)(e0 + rowb) * KC + ds * 64 + (t & 7) * 8);
    }
    __syncthreads();
    #pragma unroll
    for (int kk = 0; kk < 2; ++kk){
      bf16x8 av[4], bv[2];
      #pragma unroll
      for (int i = 0; i < 4; ++i)
        av[i] = *(const bf16x8*)&As[(i * 16 + (lane & 15)) * 72 + kk * 32 + (lane >> 4) * 8];
      #pragma unroll
      for (int q2 = 0; q2 < 2; ++q2)
        bv[q2] = *(const bf16x8*)&BW[(wn * 32 + q2 * 16 + (lane & 15)) * 72 + kk * 32 + (lane >> 4) * 8];
      #pragma unroll
      for (int i = 0; i < 4; ++i)
        #pragma unroll
        for (int q2 = 0; q2 < 2; ++q2)
          accA[i][q2] = __builtin_amdgcn_mfma_f32_16x16x32_bf16(av[i], bv[q2], accA[i][q2], 0, 0, 0);
    }
    __syncthreads();
  }
  // ---- epilogue ----
  #pragma unroll
  for (int i = 0; i < 4; ++i){
    #pragma unroll
    for (int rr = 0; rr < 4; ++rr){
      size_t gr = (size_t)b * Nn + m0 + i * 16 + (lane >> 4) * 4 + rr;
      #pragma unroll
      for (int q2 = 0; q2 < 2; ++q2){
        int col = e0 + wn * 32 + q2 * 16 + (lane & 15);
        float v = accA[i][q2][rr] + bself[col];
        outp[gr * Dd + col] = v > 0.f ? v : 0.f;
      }
    }
  }
}

extern "C" void kernel_launch(void* const* d_in, const int* in_sizes, int n_in,
                              void* d_out, int out_size, void* d_ws, size_t ws_size,
                              hipStream_t stream){
  (void)in_sizes; (void)n_in; (void)out_size; (void)ws_size;
  const float* node  = (const float*)d_in[0];
  const int*   mask  = (const int*)d_in[1];
  const int*   g[6];
  for (int i = 0; i < 6; ++i) g[i] = (const int*)d_in[2 + i];
  const float* wnw   = (const float*)d_in[8];
  const float* bnw   = (const float*)d_in[9];
  const float* wself = (const float*)d_in[10];
  const float* bself = (const float*)d_in[11];
  const float* W[6];
  for (int i = 0; i < 6; ++i) W[i] = (const float*)d_in[12 + i];

  float* out_node = (float*)d_out;
  float* out_aw   = out_node + (size_t)Bb * Nn * Dd;

  char* ws = (char*)d_ws;
  u16*      wcatT = (u16*)(ws);                    // 917,504 B
  float*    rs    = (float*)(ws + 917504);         // 65,536 B
  unsigned* Gp    = (unsigned*)(ws + 1048576);     // 6,291,456 B
  u16*      Xp    = (u16*)(ws + 7340032);          // 8,388,608 B
  u16*      Nbf   = (u16*)(ws + 15728640);         // 8,388,608 B
  u16*      Yt    = (u16*)(ws + 24117248);         // 50,331,648 B -> ends ~74.4 MB

  k_prep<<<256, 256, 0, stream>>>(wself, W[0], W[1], W[2], W[3], W[4], W[5], wcatT);

  // ---- iteration 1: raw-graph aggregation (also emits Gp, rs) ----
  k_dw<<<512, 256, 0, stream>>>(node, mask, wnw, bnw, out_aw, Nbf, Xp);
  k_ycat<<<dim3(4, 12, 32), 256, 0, stream>>>(Xp, wcatT, Yt);
  k_agg1<<<512, 256, 0, stream>>>(g[0], g[1], g[2], g[3], g[4], g[5], mask,
                                  Yt, Nbf, wcatT, bself,
                                  (unsigned char*)Gp, rs, out_node);

  // ---- iteration 2: packed-graph aggregation ----
  k_dw<<<512, 256, 0, stream>>>(out_node, mask, wnw, bnw, out_aw + Nn, Nbf, Xp);
  k_ycat<<<dim3(4, 12, 32), 256, 0, stream>>>(Xp, wcatT, Yt);
  k_agg2<<<512, 256, 0, stream>>>(Gp, Yt, Nbf, wcatT, rs, bself, out_node);
}